// Round 7
// baseline (151.673 us; speedup 1.0000x reference)
//
#include <hip/hip_runtime.h>
#include <hip/hip_bf16.h>

// ContactLoss: Möller–Trumbore parity ray-cast (x2) + nearest-neighbor anchors
// + masked tanh means. All fp32, fp-contract OFF to bit-match numpy reference.
//
// R7: mega with FOUR points per thread (R6 had 2). Halves LDS read issue per
// test (~17%->9% of VALU pipe), halves raycast block count (staging/decode
// amortization), halves tri_pre redundancy. Per-test expression tree is
// byte-identical to the absmax-0.0 lineage. 2 dispatches (harness overhead
// ~60us is node-count-insensitive per R3-R6 fits).

#define RX 0.4395064455f
#define RY 0.617598629942f
#define RZ 0.652231566745f

#define MAXCHUNK_F4 512    // LDS float4 slots; >= max(chunkA,chunkB)*4
#define PTS_PER_BLK 1024   // 4 points per thread

struct Params {
    const float* hand_verts; const int* hand_faces;
    const float* obj_verts;  const int* obj_faces;
    const int* ovsplit; const int* ofsplit;
    int* hitsA;                // [CA*B*No] pass-A per-chunk hit counts
    int* hitsB;                // [CB*B*Nh] pass-B per-chunk hit counts
    float* anchor_h; float* anchor_o; float* partials;
    unsigned int* done;
    float* out;
    int B, Nh, Fh, No, Fo;
    int pbA, CA, chunkA, blocksA;
    int pbB, CB, chunkB, blocksB;
};

// ---------------------------------------------------------------------------
// Per-triangle precompute (identical arithmetic to the absmax-0.0 lineage).
// ---------------------------------------------------------------------------
__device__ __forceinline__ void tri_pre_one(const float* __restrict__ vb,
                                            const int* __restrict__ f,
                                            float4* o) {
#pragma clang fp contract(off)
    int i0 = f[0], i1 = f[1], i2 = f[2];
    float v0x = vb[i0*3+0], v0y = vb[i0*3+1], v0z = vb[i0*3+2];
    float v1x = vb[i1*3+0], v1y = vb[i1*3+1], v1z = vb[i1*3+2];
    float v2x = vb[i2*3+0], v2y = vb[i2*3+1], v2z = vb[i2*3+2];
    float e1x = v1x - v0x, e1y = v1y - v0y, e1z = v1z - v0z;
    float e2x = v2x - v0x, e2y = v2y - v0y, e2z = v2z - v0z;
    float px = RY*e2z - RZ*e2y;
    float py = RZ*e2x - RX*e2z;
    float pz = RX*e2y - RY*e2x;
    float det = (e1x*px + e1y*py) + e1z*pz;       // ((a+b)+c) like np.sum
    float invdet = 1.0f / (det + 1e-8f);          // 0.1*TOL, IEEE div
    bool valid = !(fabsf(det) < 1e-7f);
    o[0] = make_float4(v0x, v0y, v0z, invdet);
    o[1] = make_float4(e1x, e1y, e1z, valid ? 1.0f : 0.0f);
    o[2] = make_float4(e2x, e2y, e2z, 0.0f);
    o[3] = make_float4(px,  py,  pz,  0.0f);
}

// One Möller–Trumbore test (expression tree identical to absmax-0.0 lineage).
__device__ __forceinline__ int mt_test(float qx, float qy, float qz,
                                       const float4& f0, const float4& f1,
                                       const float4& f2, const float4& f3) {
#pragma clang fp contract(off)
    float tvx = qx - f0.x, tvy = qy - f0.y, tvz = qz - f0.z;
    float u  = ((tvx*f3.x + tvy*f3.y) + tvz*f3.z) * f0.w;
    float qvx = tvy*f1.z - tvz*f1.y;
    float qvy = tvz*f1.x - tvx*f1.z;
    float qvz = tvx*f1.y - tvy*f1.x;
    float v  = ((qvx*RX + qvy*RY) + qvz*RZ) * f0.w;
    float tt = ((f2.x*qvx + f2.y*qvy) + f2.z*qvz) * f0.w;
    bool hit = (u > 0.0f) && (u < 1.0f) && (v > 0.0f) &&
               ((u + v) < 1.0f) && (tt > 1e-7f) && (f1.w != 0.0f);
    return hit ? 1 : 0;
}

// ---------------------------------------------------------------------------
// One raycast virtual block: triangle chunk built inline into LDS, each
// thread tests FOUR points (quarters LDS read traffic per test).
// ---------------------------------------------------------------------------
__device__ __forceinline__ void raycast_vb(const Params& p, int vbid, int tid,
                                           float4* s_tri) {
#pragma clang fp contract(off)
    const float* pts; const float* tverts; const int* tfaces; int* slots;
    int P, T, Nv, c, pb, b, chunk, tlim, plim;
    if (vbid < p.blocksA) {
        int per_b = p.pbA * p.CA;
        b  = vbid / per_b;
        int r = vbid - b * per_b;
        c  = r / p.pbA;
        pb = r - c * p.pbA;
        pts = p.obj_verts; tverts = p.hand_verts; tfaces = p.hand_faces;
        slots = p.hitsA;
        P = p.No; T = p.Fh; Nv = p.Nh; chunk = p.chunkA;
        tlim = p.Fh; plim = min(p.No, p.ovsplit[b]);   // invalid pts never read
    } else {
        int j = vbid - p.blocksA;
        int per_b = p.pbB * p.CB;
        b  = j / per_b;
        int r = j - b * per_b;
        c  = r / p.pbB;
        pb = r - c * p.pbB;
        pts = p.hand_verts; tverts = p.obj_verts; tfaces = p.obj_faces;
        slots = p.hitsB;
        P = p.Nh; T = p.Fo; Nv = p.No; chunk = p.chunkB;
        tlim = min(p.Fo, p.ofsplit[b]); plim = p.Nh;
    }

    int tStart = c * chunk;
    if (tStart >= tlim) return;               // block-uniform (slots unread)
    if (pb * PTS_PER_BLK >= plim) return;     // block-uniform (slots unread)
    int nTri = min(tStart + chunk, tlim) - tStart;

    if (tid < nTri) {
        int t = tStart + tid;
        tri_pre_one(tverts + (size_t)b * Nv * 3,
                    tfaces + ((size_t)b * T + t) * 3,
                    s_tri + (size_t)tid * 4);
    }

    int p0 = pb * PTS_PER_BLK + tid;
    float qx[4], qy[4], qz[4];
    bool act[4];
    #pragma unroll
    for (int k = 0; k < 4; ++k) {
        int pk = p0 + k * 256;
        act[k] = pk < plim;
        qx[k] = 0.f; qy[k] = 0.f; qz[k] = 0.f;
        if (act[k]) {
            const float* q = pts + ((size_t)b * P + pk) * 3;
            qx[k] = q[0]; qy[k] = q[1]; qz[k] = q[2];
        }
    }
    __syncthreads();

    if (!act[0]) return;                      // act[0] false => all false
    int cnt[4] = {0, 0, 0, 0};
    for (int i = 0; i < nTri; ++i) {
        const float4 f0 = s_tri[(i<<2)+0];
        const float4 f1 = s_tri[(i<<2)+1];
        const float4 f2 = s_tri[(i<<2)+2];
        const float4 f3 = s_tri[(i<<2)+3];
        #pragma unroll
        for (int k = 0; k < 4; ++k)
            cnt[k] += mt_test(qx[k], qy[k], qz[k], f0, f1, f2, f3);
    }
    int* base = slots + ((size_t)(c * p.B + b)) * P;
    #pragma unroll
    for (int k = 0; k < 4; ++k)
        if (act[k]) base[p0 + k * 256] = cnt[k];   // plain stores, no atomics
}

// ---------------------------------------------------------------------------
// One argmin wave. Packed (dist<<32)|idx min => np.argmin tie-break.
// ---------------------------------------------------------------------------
__device__ __forceinline__ void min_one(const Params& p, int w, int lane) {
#pragma clang fp contract(off)
    int nHand = p.B * p.Nh;
    const float* refv; const float* loopv; int loopN; float* outp;
    if (w < nHand) {
        int b = w / p.Nh;
        int n = w - b * p.Nh;
        refv  = p.hand_verts + ((size_t)b * p.Nh + n) * 3;
        loopv = p.obj_verts + (size_t)b * p.No * 3;
        loopN = p.ovsplit[b];
        outp  = p.anchor_h + (size_t)b * p.Nh + n;
    } else {
        int j = w - nHand;
        int b = j / p.No;
        int m = j - b * p.No;
        if (m >= p.ovsplit[b]) return;
        refv  = p.obj_verts + ((size_t)b * p.No + m) * 3;
        loopv = p.hand_verts + (size_t)b * p.Nh * 3;
        loopN = p.Nh;
        outp  = p.anchor_o + (size_t)b * p.No + m;
    }
    float hx = refv[0], hy = refv[1], hz = refv[2];
    float rx = (hx*hx + hy*hy) + hz*hz;
    unsigned long long best = ~0ull;
    for (int m = lane; m < loopN; m += 64) {
        float ox = loopv[m*3+0], oy = loopv[m*3+1], oz = loopv[m*3+2];
        float ry = (ox*ox + oy*oy) + oz*oz;
        float zz = (hx*ox + hy*oy) + hz*oz;
        float d = (rx + ry) - 2.0f * zz;
        unsigned long long e = ((unsigned long long)__float_as_uint(d) << 32) | (unsigned)m;
        if (e < best) best = e;
    }
    for (int off = 32; off > 0; off >>= 1) {
        unsigned long long o = __shfl_xor(best, off, 64);
        if (o < best) best = o;
    }
    if (lane == 0) {
        int idx = (best == ~0ull) ? 0 : (int)(best & 0xffffffffu);
        const float* cv = loopv + (size_t)idx * 3;
        float dx = cv[0] - hx, dy = cv[1] - hy, dz = cv[2] - hz;
        *outp = sqrtf((dx*dx + dy*dy) + dz*dz);
    }
}

// ---------------------------------------------------------------------------
// mega: [raycast VBs | argmin blocks] — no tail sync; resets done counter.
// ---------------------------------------------------------------------------
__global__ __launch_bounds__(256) void mega(Params p) {
    __shared__ float4 s_tri[MAXCHUNK_F4];
    const int tid = threadIdx.x;
    const int bid = blockIdx.x;
    if (bid == 0 && tid == 0) *p.done = 0u;   // visible to reduce_fin at boundary
    const int nRay = p.blocksA + p.blocksB;
    if (bid < nRay) {
        raycast_vb(p, bid, tid, s_tri);
    } else {
        int w = (bid - nRay) * 4 + (tid >> 6);
        if (w < p.B * (p.Nh + p.No)) min_one(p, w, tid & 63);
    }
}

// ---------------------------------------------------------------------------
// reduce_fin: block b = batch b. Sums per-chunk slots (parity) + tanh means;
// last-done block (8-way counter + fences) finalizes.
// ---------------------------------------------------------------------------
__global__ __launch_bounds__(1024) void reduce_fin(Params p) {
    const int b = blockIdx.x, tid = threadIdx.x;
    const int wave = tid >> 6, lane = tid & 63;
    float s0=0.f,s1=0.f,s2=0.f,s3=0.f,s4=0.f,s5=0.f;

    int tlimB = min(p.Fo, p.ofsplit[b]);
    int nCB = (tlimB + p.chunkB - 1) / p.chunkB;        // valid pass-B chunks
    for (int n = tid; n < p.Nh; n += 1024) {
        int par = 0;
        for (int c = 0; c < nCB; ++c)
            par += p.hitsB[((size_t)(c * p.B + b)) * p.Nh + n];
        bool ext = (par & 1) == 0;
        float val = 25.0f * tanhf(p.anchor_h[(size_t)b*p.Nh + n] / 25.0f);
        if (ext) { s0 += val; s1 += 1.0f; } else { s2 += val; s3 += 1.0f; }
    }
    int split = p.ovsplit[b];
    for (int m = tid; m < split; m += 1024) {
        int par = 0;
        for (int c = 0; c < p.CA; ++c)
            par += p.hitsA[((size_t)(c * p.B + b)) * p.No + m];
        if (par & 1) {                                   // interior & valid
            s4 += 25.0f * tanhf(p.anchor_o[(size_t)b*p.No + m] / 25.0f);
            s5 += 1.0f;
        }
    }
    for (int off = 32; off > 0; off >>= 1) {
        s0 += __shfl_xor(s0, off, 64);
        s1 += __shfl_xor(s1, off, 64);
        s2 += __shfl_xor(s2, off, 64);
        s3 += __shfl_xor(s3, off, 64);
        s4 += __shfl_xor(s4, off, 64);
        s5 += __shfl_xor(s5, off, 64);
    }
    __shared__ float red[16][6];
    __shared__ bool s_last;
    if (lane == 0) {
        red[wave][0]=s0; red[wave][1]=s1; red[wave][2]=s2;
        red[wave][3]=s3; red[wave][4]=s4; red[wave][5]=s5;
    }
    __syncthreads();
    if (tid == 0) {
        float t0=0.f,t1=0.f,t2=0.f,t3=0.f,t4=0.f,t5=0.f;
        for (int wv = 0; wv < 16; ++wv) {
            t0 += red[wv][0]; t1 += red[wv][1]; t2 += red[wv][2];
            t3 += red[wv][3]; t4 += red[wv][4]; t5 += red[wv][5];
        }
        p.out[2 + b]  = (t1 > 0.f) ? t0 / fmaxf(t1, 1.f) : 0.f;
        float ph      = (t3 > 0.f) ? t2 / fmaxf(t3, 1.f) : 0.f;
        float po      = (t5 > 0.f) ? t4 / fmaxf(t5, 1.f) : 0.f;
        p.out[10 + b] = ph + po;
        float* pp = p.partials + b * 6;
        pp[0]=t0; pp[1]=t1; pp[2]=t2; pp[3]=t3; pp[4]=t4; pp[5]=t5;
        __threadfence();                     // release partials
        unsigned int old = atomicAdd(p.done, 1u);
        s_last = (old == (unsigned int)(gridDim.x - 1));
    }
    __syncthreads();
    if (!s_last || tid != 0) return;
    __threadfence();                         // acquire others' partials
    float sm=0.f,cm=0.f,sph=0.f,cph=0.f,spo=0.f,cpo=0.f;
    for (int bb = 0; bb < p.B; ++bb) {
        const float* pp = p.partials + bb * 6;
        sm  += pp[0]; cm  += pp[1]; sph += pp[2];
        cph += pp[3]; spo += pp[4]; cpo += pp[5];
    }
    float missed = (cm  > 0.f) ? sm  / fmaxf(cm , 1.f) : 0.f;
    float ph     = (cph > 0.f) ? sph / fmaxf(cph, 1.f) : 0.f;
    float po     = (cpo > 0.f) ? spo / fmaxf(cpo, 1.f) : 0.f;
    p.out[0] = missed;
    p.out[1] = ph + po;
}

// ---------------------------------------------------------------------------
extern "C" void kernel_launch(void* const* d_in, const int* in_sizes, int n_in,
                              void* d_out, int out_size, void* d_ws, size_t ws_size,
                              hipStream_t stream) {
    Params p;
    p.hand_verts = (const float*)d_in[0];
    p.hand_faces = (const int*)d_in[1];
    p.obj_verts  = (const float*)d_in[2];
    p.obj_faces  = (const int*)d_in[3];
    p.ovsplit    = (const int*)d_in[4];
    p.ofsplit    = (const int*)d_in[5];
    p.out        = (float*)d_out;

    p.B  = in_sizes[4];
    p.Nh = in_sizes[0] / (3 * p.B);
    p.Fh = in_sizes[1] / (3 * p.B);
    p.No = in_sizes[2] / (3 * p.B);
    p.Fo = in_sizes[3] / (3 * p.B);

    p.CA = 16; p.CB = 32;
    p.chunkA = (p.Fh + p.CA - 1) / p.CA;       // 97  for Fh=1538 (388 f4 <= 512)
    p.chunkB = (p.Fo + p.CB - 1) / p.CB;       // 125 for Fo=4000 (500 f4 <= 512)
    p.pbA = (p.No + PTS_PER_BLK - 1) / PTS_PER_BLK;   // 2
    p.pbB = (p.Nh + PTS_PER_BLK - 1) / PTS_PER_BLK;   // 1
    p.blocksA = p.pbA * p.CA * p.B;            // 256
    p.blocksB = p.pbB * p.CB * p.B;            // 256

    char* ws = (char*)d_ws;
    size_t off = 0;
    auto alloc = [&](size_t bytes) -> void* {
        void* q = ws + off;
        off = (off + bytes + 255) & ~(size_t)255;
        return q;
    };
    p.hitsA    = (int*)   alloc((size_t)p.CA * p.B * p.No * sizeof(int));
    p.hitsB    = (int*)   alloc((size_t)p.CB * p.B * p.Nh * sizeof(int));
    p.anchor_h = (float*) alloc((size_t)p.B * p.Nh * sizeof(float));
    p.anchor_o = (float*) alloc((size_t)p.B * p.No * sizeof(float));
    p.partials = (float*) alloc((size_t)p.B * 6 * sizeof(float));
    p.done     = (unsigned int*)alloc(sizeof(unsigned int));

    int totalMin   = p.B * (p.Nh + p.No);
    int nMinBlocks = (totalMin + 3) / 4;       // 4 argmin waves per block
    int grid = p.blocksA + p.blocksB + nMinBlocks;

    mega<<<grid, 256, 0, stream>>>(p);
    reduce_fin<<<p.B, 1024, 0, stream>>>(p);
}

// Round 8
// 140.138 us; speedup vs baseline: 1.0823x; 1.0823x over previous
//
#include <hip/hip_runtime.h>
#include <hip/hip_bf16.h>

// ContactLoss: Möller–Trumbore parity ray-cast (x2) + nearest-neighbor anchors
// + masked tanh means. All fp32, fp-contract OFF to bit-match numpy reference.
//
// R8: R6 structure (2 pts/thread — R7 proved 4 pts regresses: compiler
// serialization at VGPR=32 + lost block-level early-outs) with the triangle
// inner loop UNROLLED x2: hit counters are integers, so tri-loop order is
// freely reorderable with zero numerical risk; 8 LDS reads issued up front
// per 4 tests doubles VALU run-length per lgkm wait. Per-test fp expression
// tree remains byte-identical to the absmax-0.0 lineage. 2 dispatches.

#define RX 0.4395064455f
#define RY 0.617598629942f
#define RZ 0.652231566745f

#define MAXCHUNK_F4 512   // LDS float4 slots; >= max(chunkA,chunkB)*4
#define PTS_PER_BLK 512   // 2 points per thread

struct Params {
    const float* hand_verts; const int* hand_faces;
    const float* obj_verts;  const int* obj_faces;
    const int* ovsplit; const int* ofsplit;
    int* hitsA;                // [CA*B*No] pass-A per-chunk hit counts
    int* hitsB;                // [CB*B*Nh] pass-B per-chunk hit counts
    float* anchor_h; float* anchor_o; float* partials;
    unsigned int* done;
    float* out;
    int B, Nh, Fh, No, Fo;
    int pbA, CA, chunkA, blocksA;
    int pbB, CB, chunkB, blocksB;
};

// ---------------------------------------------------------------------------
// Per-triangle precompute (identical arithmetic to the absmax-0.0 lineage).
// ---------------------------------------------------------------------------
__device__ __forceinline__ void tri_pre_one(const float* __restrict__ vb,
                                            const int* __restrict__ f,
                                            float4* o) {
#pragma clang fp contract(off)
    int i0 = f[0], i1 = f[1], i2 = f[2];
    float v0x = vb[i0*3+0], v0y = vb[i0*3+1], v0z = vb[i0*3+2];
    float v1x = vb[i1*3+0], v1y = vb[i1*3+1], v1z = vb[i1*3+2];
    float v2x = vb[i2*3+0], v2y = vb[i2*3+1], v2z = vb[i2*3+2];
    float e1x = v1x - v0x, e1y = v1y - v0y, e1z = v1z - v0z;
    float e2x = v2x - v0x, e2y = v2y - v0y, e2z = v2z - v0z;
    float px = RY*e2z - RZ*e2y;
    float py = RZ*e2x - RX*e2z;
    float pz = RX*e2y - RY*e2x;
    float det = (e1x*px + e1y*py) + e1z*pz;       // ((a+b)+c) like np.sum
    float invdet = 1.0f / (det + 1e-8f);          // 0.1*TOL, IEEE div
    bool valid = !(fabsf(det) < 1e-7f);
    o[0] = make_float4(v0x, v0y, v0z, invdet);
    o[1] = make_float4(e1x, e1y, e1z, valid ? 1.0f : 0.0f);
    o[2] = make_float4(e2x, e2y, e2z, 0.0f);
    o[3] = make_float4(px,  py,  pz,  0.0f);
}

// One Möller–Trumbore test (expression tree identical to absmax-0.0 lineage).
__device__ __forceinline__ int mt_test(float qx, float qy, float qz,
                                       const float4& f0, const float4& f1,
                                       const float4& f2, const float4& f3) {
#pragma clang fp contract(off)
    float tvx = qx - f0.x, tvy = qy - f0.y, tvz = qz - f0.z;
    float u  = ((tvx*f3.x + tvy*f3.y) + tvz*f3.z) * f0.w;
    float qvx = tvy*f1.z - tvz*f1.y;
    float qvy = tvz*f1.x - tvx*f1.z;
    float qvz = tvx*f1.y - tvy*f1.x;
    float v  = ((qvx*RX + qvy*RY) + qvz*RZ) * f0.w;
    float tt = ((f2.x*qvx + f2.y*qvy) + f2.z*qvz) * f0.w;
    bool hit = (u > 0.0f) && (u < 1.0f) && (v > 0.0f) &&
               ((u + v) < 1.0f) && (tt > 1e-7f) && (f1.w != 0.0f);
    return hit ? 1 : 0;
}

// ---------------------------------------------------------------------------
// One raycast virtual block: triangle chunk built inline into LDS, each
// thread tests TWO points; triangle loop unrolled x2 (integer-exact reorder).
// ---------------------------------------------------------------------------
__device__ __forceinline__ void raycast_vb(const Params& p, int vbid, int tid,
                                           float4* s_tri) {
#pragma clang fp contract(off)
    const float* pts; const float* tverts; const int* tfaces; int* slots;
    int P, T, Nv, c, pb, b, chunk, tlim, plim;
    if (vbid < p.blocksA) {
        int per_b = p.pbA * p.CA;
        b  = vbid / per_b;
        int r = vbid - b * per_b;
        c  = r / p.pbA;
        pb = r - c * p.pbA;
        pts = p.obj_verts; tverts = p.hand_verts; tfaces = p.hand_faces;
        slots = p.hitsA;
        P = p.No; T = p.Fh; Nv = p.Nh; chunk = p.chunkA;
        tlim = p.Fh; plim = min(p.No, p.ovsplit[b]);   // invalid pts never read
    } else {
        int j = vbid - p.blocksA;
        int per_b = p.pbB * p.CB;
        b  = j / per_b;
        int r = j - b * per_b;
        c  = r / p.pbB;
        pb = r - c * p.pbB;
        pts = p.hand_verts; tverts = p.obj_verts; tfaces = p.obj_faces;
        slots = p.hitsB;
        P = p.Nh; T = p.Fo; Nv = p.No; chunk = p.chunkB;
        tlim = min(p.Fo, p.ofsplit[b]); plim = p.Nh;
    }

    int tStart = c * chunk;
    if (tStart >= tlim) return;               // block-uniform (slots unread)
    if (pb * PTS_PER_BLK >= plim) return;     // block-uniform (slots unread)
    int nTri = min(tStart + chunk, tlim) - tStart;

    if (tid < nTri) {
        int t = tStart + tid;
        tri_pre_one(tverts + (size_t)b * Nv * 3,
                    tfaces + ((size_t)b * T + t) * 3,
                    s_tri + (size_t)tid * 4);
    }

    int p1 = pb * PTS_PER_BLK + tid;
    int p2 = p1 + 256;
    bool act1 = p1 < plim, act2 = p2 < plim;
    float q1x = 0.f, q1y = 0.f, q1z = 0.f;
    float q2x = 0.f, q2y = 0.f, q2z = 0.f;
    if (act1) {
        const float* q = pts + ((size_t)b * P + p1) * 3;
        q1x = q[0]; q1y = q[1]; q1z = q[2];
    }
    if (act2) {
        const float* q = pts + ((size_t)b * P + p2) * 3;
        q2x = q[0]; q2y = q[1]; q2z = q[2];
    }
    __syncthreads();

    if (!act1) return;                        // act1 false => act2 false
    int cnt1 = 0, cnt2 = 0;
    int i = 0;
    for (; i + 2 <= nTri; i += 2) {
        const float4 a0 = s_tri[(i<<2)+0];
        const float4 a1 = s_tri[(i<<2)+1];
        const float4 a2 = s_tri[(i<<2)+2];
        const float4 a3 = s_tri[(i<<2)+3];
        const float4 b0 = s_tri[(i<<2)+4];
        const float4 b1 = s_tri[(i<<2)+5];
        const float4 b2 = s_tri[(i<<2)+6];
        const float4 b3 = s_tri[(i<<2)+7];
        cnt1 += mt_test(q1x, q1y, q1z, a0, a1, a2, a3);
        cnt2 += mt_test(q2x, q2y, q2z, a0, a1, a2, a3);
        cnt1 += mt_test(q1x, q1y, q1z, b0, b1, b2, b3);
        cnt2 += mt_test(q2x, q2y, q2z, b0, b1, b2, b3);
    }
    if (i < nTri) {
        const float4 a0 = s_tri[(i<<2)+0];
        const float4 a1 = s_tri[(i<<2)+1];
        const float4 a2 = s_tri[(i<<2)+2];
        const float4 a3 = s_tri[(i<<2)+3];
        cnt1 += mt_test(q1x, q1y, q1z, a0, a1, a2, a3);
        cnt2 += mt_test(q2x, q2y, q2z, a0, a1, a2, a3);
    }
    int* base = slots + ((size_t)(c * p.B + b)) * P;
    base[p1] = cnt1;                          // plain stores, no atomics
    if (act2) base[p2] = cnt2;
}

// ---------------------------------------------------------------------------
// One argmin wave. Packed (dist<<32)|idx min => np.argmin tie-break.
// ---------------------------------------------------------------------------
__device__ __forceinline__ void min_one(const Params& p, int w, int lane) {
#pragma clang fp contract(off)
    int nHand = p.B * p.Nh;
    const float* refv; const float* loopv; int loopN; float* outp;
    if (w < nHand) {
        int b = w / p.Nh;
        int n = w - b * p.Nh;
        refv  = p.hand_verts + ((size_t)b * p.Nh + n) * 3;
        loopv = p.obj_verts + (size_t)b * p.No * 3;
        loopN = p.ovsplit[b];
        outp  = p.anchor_h + (size_t)b * p.Nh + n;
    } else {
        int j = w - nHand;
        int b = j / p.No;
        int m = j - b * p.No;
        if (m >= p.ovsplit[b]) return;
        refv  = p.obj_verts + ((size_t)b * p.No + m) * 3;
        loopv = p.hand_verts + (size_t)b * p.Nh * 3;
        loopN = p.Nh;
        outp  = p.anchor_o + (size_t)b * p.No + m;
    }
    float hx = refv[0], hy = refv[1], hz = refv[2];
    float rx = (hx*hx + hy*hy) + hz*hz;
    unsigned long long best = ~0ull;
    for (int m = lane; m < loopN; m += 64) {
        float ox = loopv[m*3+0], oy = loopv[m*3+1], oz = loopv[m*3+2];
        float ry = (ox*ox + oy*oy) + oz*oz;
        float zz = (hx*ox + hy*oy) + hz*oz;
        float d = (rx + ry) - 2.0f * zz;
        unsigned long long e = ((unsigned long long)__float_as_uint(d) << 32) | (unsigned)m;
        if (e < best) best = e;
    }
    for (int off = 32; off > 0; off >>= 1) {
        unsigned long long o = __shfl_xor(best, off, 64);
        if (o < best) best = o;
    }
    if (lane == 0) {
        int idx = (best == ~0ull) ? 0 : (int)(best & 0xffffffffu);
        const float* cv = loopv + (size_t)idx * 3;
        float dx = cv[0] - hx, dy = cv[1] - hy, dz = cv[2] - hz;
        *outp = sqrtf((dx*dx + dy*dy) + dz*dz);
    }
}

// ---------------------------------------------------------------------------
// mega: [raycast VBs | argmin blocks] — no tail sync; resets done counter.
// ---------------------------------------------------------------------------
__global__ __launch_bounds__(256) void mega(Params p) {
    __shared__ float4 s_tri[MAXCHUNK_F4];
    const int tid = threadIdx.x;
    const int bid = blockIdx.x;
    if (bid == 0 && tid == 0) *p.done = 0u;   // visible to reduce_fin at boundary
    const int nRay = p.blocksA + p.blocksB;
    if (bid < nRay) {
        raycast_vb(p, bid, tid, s_tri);
    } else {
        int w = (bid - nRay) * 4 + (tid >> 6);
        if (w < p.B * (p.Nh + p.No)) min_one(p, w, tid & 63);
    }
}

// ---------------------------------------------------------------------------
// reduce_fin: block b = batch b. Sums per-chunk slots (parity) + tanh means;
// last-done block (8-way counter + fences — cheap at 8 blocks) finalizes.
// ---------------------------------------------------------------------------
__global__ __launch_bounds__(1024) void reduce_fin(Params p) {
    const int b = blockIdx.x, tid = threadIdx.x;
    const int wave = tid >> 6, lane = tid & 63;
    float s0=0.f,s1=0.f,s2=0.f,s3=0.f,s4=0.f,s5=0.f;

    int tlimB = min(p.Fo, p.ofsplit[b]);
    int nCB = (tlimB + p.chunkB - 1) / p.chunkB;        // valid pass-B chunks
    for (int n = tid; n < p.Nh; n += 1024) {
        int par = 0;
        for (int c = 0; c < nCB; ++c)
            par += p.hitsB[((size_t)(c * p.B + b)) * p.Nh + n];
        bool ext = (par & 1) == 0;
        float val = 25.0f * tanhf(p.anchor_h[(size_t)b*p.Nh + n] / 25.0f);
        if (ext) { s0 += val; s1 += 1.0f; } else { s2 += val; s3 += 1.0f; }
    }
    int split = p.ovsplit[b];
    for (int m = tid; m < split; m += 1024) {
        int par = 0;
        for (int c = 0; c < p.CA; ++c)
            par += p.hitsA[((size_t)(c * p.B + b)) * p.No + m];
        if (par & 1) {                                   // interior & valid
            s4 += 25.0f * tanhf(p.anchor_o[(size_t)b*p.No + m] / 25.0f);
            s5 += 1.0f;
        }
    }
    for (int off = 32; off > 0; off >>= 1) {
        s0 += __shfl_xor(s0, off, 64);
        s1 += __shfl_xor(s1, off, 64);
        s2 += __shfl_xor(s2, off, 64);
        s3 += __shfl_xor(s3, off, 64);
        s4 += __shfl_xor(s4, off, 64);
        s5 += __shfl_xor(s5, off, 64);
    }
    __shared__ float red[16][6];
    __shared__ bool s_last;
    if (lane == 0) {
        red[wave][0]=s0; red[wave][1]=s1; red[wave][2]=s2;
        red[wave][3]=s3; red[wave][4]=s4; red[wave][5]=s5;
    }
    __syncthreads();
    if (tid == 0) {
        float t0=0.f,t1=0.f,t2=0.f,t3=0.f,t4=0.f,t5=0.f;
        for (int wv = 0; wv < 16; ++wv) {
            t0 += red[wv][0]; t1 += red[wv][1]; t2 += red[wv][2];
            t3 += red[wv][3]; t4 += red[wv][4]; t5 += red[wv][5];
        }
        p.out[2 + b]  = (t1 > 0.f) ? t0 / fmaxf(t1, 1.f) : 0.f;
        float ph      = (t3 > 0.f) ? t2 / fmaxf(t3, 1.f) : 0.f;
        float po      = (t5 > 0.f) ? t4 / fmaxf(t5, 1.f) : 0.f;
        p.out[10 + b] = ph + po;
        float* pp = p.partials + b * 6;
        pp[0]=t0; pp[1]=t1; pp[2]=t2; pp[3]=t3; pp[4]=t4; pp[5]=t5;
        __threadfence();                     // release partials
        unsigned int old = atomicAdd(p.done, 1u);
        s_last = (old == (unsigned int)(gridDim.x - 1));
    }
    __syncthreads();
    if (!s_last || tid != 0) return;
    __threadfence();                         // acquire others' partials
    float sm=0.f,cm=0.f,sph=0.f,cph=0.f,spo=0.f,cpo=0.f;
    for (int bb = 0; bb < p.B; ++bb) {
        const float* pp = p.partials + bb * 6;
        sm  += pp[0]; cm  += pp[1]; sph += pp[2];
        cph += pp[3]; spo += pp[4]; cpo += pp[5];
    }
    float missed = (cm  > 0.f) ? sm  / fmaxf(cm , 1.f) : 0.f;
    float ph     = (cph > 0.f) ? sph / fmaxf(cph, 1.f) : 0.f;
    float po     = (cpo > 0.f) ? spo / fmaxf(cpo, 1.f) : 0.f;
    p.out[0] = missed;
    p.out[1] = ph + po;
}

// ---------------------------------------------------------------------------
extern "C" void kernel_launch(void* const* d_in, const int* in_sizes, int n_in,
                              void* d_out, int out_size, void* d_ws, size_t ws_size,
                              hipStream_t stream) {
    Params p;
    p.hand_verts = (const float*)d_in[0];
    p.hand_faces = (const int*)d_in[1];
    p.obj_verts  = (const float*)d_in[2];
    p.obj_faces  = (const int*)d_in[3];
    p.ovsplit    = (const int*)d_in[4];
    p.ofsplit    = (const int*)d_in[5];
    p.out        = (float*)d_out;

    p.B  = in_sizes[4];
    p.Nh = in_sizes[0] / (3 * p.B);
    p.Fh = in_sizes[1] / (3 * p.B);
    p.No = in_sizes[2] / (3 * p.B);
    p.Fo = in_sizes[3] / (3 * p.B);

    p.CA = 16; p.CB = 32;
    p.chunkA = (p.Fh + p.CA - 1) / p.CA;       // 97  for Fh=1538 (388 f4 <= 512)
    p.chunkB = (p.Fo + p.CB - 1) / p.CB;       // 125 for Fo=4000 (500 f4 <= 512)
    p.pbA = (p.No + PTS_PER_BLK - 1) / PTS_PER_BLK;   // 4
    p.pbB = (p.Nh + PTS_PER_BLK - 1) / PTS_PER_BLK;   // 2
    p.blocksA = p.pbA * p.CA * p.B;            // 512
    p.blocksB = p.pbB * p.CB * p.B;            // 512

    char* ws = (char*)d_ws;
    size_t off = 0;
    auto alloc = [&](size_t bytes) -> void* {
        void* q = ws + off;
        off = (off + bytes + 255) & ~(size_t)255;
        return q;
    };
    p.hitsA    = (int*)   alloc((size_t)p.CA * p.B * p.No * sizeof(int));
    p.hitsB    = (int*)   alloc((size_t)p.CB * p.B * p.Nh * sizeof(int));
    p.anchor_h = (float*) alloc((size_t)p.B * p.Nh * sizeof(float));
    p.anchor_o = (float*) alloc((size_t)p.B * p.No * sizeof(float));
    p.partials = (float*) alloc((size_t)p.B * 6 * sizeof(float));
    p.done     = (unsigned int*)alloc(sizeof(unsigned int));

    int totalMin   = p.B * (p.Nh + p.No);
    int nMinBlocks = (totalMin + 3) / 4;       // 4 argmin waves per block
    int grid = p.blocksA + p.blocksB + nMinBlocks;

    mega<<<grid, 256, 0, stream>>>(p);
    reduce_fin<<<p.B, 1024, 0, stream>>>(p);
}

// Round 9
// 135.598 us; speedup vs baseline: 1.1186x; 1.0335x over previous
//
#include <hip/hip_runtime.h>
#include <hip/hip_bf16.h>

// ContactLoss: Möller–Trumbore parity ray-cast (x2) + nearest-neighbor anchors
// + masked tanh means. All fp32, fp-contract OFF to bit-match numpy reference.
//
// R9 = R6 revert (proven best: 133.7us, absmax 0.0). Local optimum bracketed:
//  - R7 (4 pts/thread): 83us mega — compiler serialization + lost early-outs.
//  - R8 (tri-unroll x2): 70us mega — VGPR 36->64 occupancy cliff (m69).
//  - R6 (this): 65us mega, VGPR 36, occ 53%, VALUBusy 73% ~= inst-count floor.
// Budget: mega 65 + reduce_fin ~5 + ~60us fixed harness overhead (fitted
// R3-R8, node-count-insensitive) ~= 134us.
//
// Structure: 2 dispatches.
//  - mega:       [raycast VBs (2 pts/thread, tri chunk built inline into LDS,
//                 private per-(chunk,batch,point) hit slots, plain stores,
//                 no atomics/fences) | argmin blocks]. Resets done counter.
//  - reduce_fin: 8 blocks (one per batch) sum chunk slots (parity) + tanh
//                means; last block (8-way done counter + fences) finalizes.

#define RX 0.4395064455f
#define RY 0.617598629942f
#define RZ 0.652231566745f

#define MAXCHUNK_F4 512   // LDS float4 slots; >= max(chunkA,chunkB)*4
#define PTS_PER_BLK 512   // 2 points per thread

struct Params {
    const float* hand_verts; const int* hand_faces;
    const float* obj_verts;  const int* obj_faces;
    const int* ovsplit; const int* ofsplit;
    int* hitsA;                // [CA*B*No] pass-A per-chunk hit counts
    int* hitsB;                // [CB*B*Nh] pass-B per-chunk hit counts
    float* anchor_h; float* anchor_o; float* partials;
    unsigned int* done;
    float* out;
    int B, Nh, Fh, No, Fo;
    int pbA, CA, chunkA, blocksA;
    int pbB, CB, chunkB, blocksB;
};

// ---------------------------------------------------------------------------
// Per-triangle precompute (identical arithmetic to the absmax-0.0 lineage).
// ---------------------------------------------------------------------------
__device__ __forceinline__ void tri_pre_one(const float* __restrict__ vb,
                                            const int* __restrict__ f,
                                            float4* o) {
#pragma clang fp contract(off)
    int i0 = f[0], i1 = f[1], i2 = f[2];
    float v0x = vb[i0*3+0], v0y = vb[i0*3+1], v0z = vb[i0*3+2];
    float v1x = vb[i1*3+0], v1y = vb[i1*3+1], v1z = vb[i1*3+2];
    float v2x = vb[i2*3+0], v2y = vb[i2*3+1], v2z = vb[i2*3+2];
    float e1x = v1x - v0x, e1y = v1y - v0y, e1z = v1z - v0z;
    float e2x = v2x - v0x, e2y = v2y - v0y, e2z = v2z - v0z;
    float px = RY*e2z - RZ*e2y;
    float py = RZ*e2x - RX*e2z;
    float pz = RX*e2y - RY*e2x;
    float det = (e1x*px + e1y*py) + e1z*pz;       // ((a+b)+c) like np.sum
    float invdet = 1.0f / (det + 1e-8f);          // 0.1*TOL, IEEE div
    bool valid = !(fabsf(det) < 1e-7f);
    o[0] = make_float4(v0x, v0y, v0z, invdet);
    o[1] = make_float4(e1x, e1y, e1z, valid ? 1.0f : 0.0f);
    o[2] = make_float4(e2x, e2y, e2z, 0.0f);
    o[3] = make_float4(px,  py,  pz,  0.0f);
}

// One Möller–Trumbore test (expression tree identical to absmax-0.0 lineage).
__device__ __forceinline__ int mt_test(float qx, float qy, float qz,
                                       const float4& f0, const float4& f1,
                                       const float4& f2, const float4& f3) {
#pragma clang fp contract(off)
    float tvx = qx - f0.x, tvy = qy - f0.y, tvz = qz - f0.z;
    float u  = ((tvx*f3.x + tvy*f3.y) + tvz*f3.z) * f0.w;
    float qvx = tvy*f1.z - tvz*f1.y;
    float qvy = tvz*f1.x - tvx*f1.z;
    float qvz = tvx*f1.y - tvy*f1.x;
    float v  = ((qvx*RX + qvy*RY) + qvz*RZ) * f0.w;
    float tt = ((f2.x*qvx + f2.y*qvy) + f2.z*qvz) * f0.w;
    bool hit = (u > 0.0f) && (u < 1.0f) && (v > 0.0f) &&
               ((u + v) < 1.0f) && (tt > 1e-7f) && (f1.w != 0.0f);
    return hit ? 1 : 0;
}

// ---------------------------------------------------------------------------
// One raycast virtual block: triangle chunk built inline into LDS, each
// thread tests TWO points (halves LDS read traffic per test).
// ---------------------------------------------------------------------------
__device__ __forceinline__ void raycast_vb(const Params& p, int vbid, int tid,
                                           float4* s_tri) {
#pragma clang fp contract(off)
    const float* pts; const float* tverts; const int* tfaces; int* slots;
    int P, T, Nv, c, pb, b, chunk, tlim, plim;
    if (vbid < p.blocksA) {
        int per_b = p.pbA * p.CA;
        b  = vbid / per_b;
        int r = vbid - b * per_b;
        c  = r / p.pbA;
        pb = r - c * p.pbA;
        pts = p.obj_verts; tverts = p.hand_verts; tfaces = p.hand_faces;
        slots = p.hitsA;
        P = p.No; T = p.Fh; Nv = p.Nh; chunk = p.chunkA;
        tlim = p.Fh; plim = min(p.No, p.ovsplit[b]);   // invalid pts never read
    } else {
        int j = vbid - p.blocksA;
        int per_b = p.pbB * p.CB;
        b  = j / per_b;
        int r = j - b * per_b;
        c  = r / p.pbB;
        pb = r - c * p.pbB;
        pts = p.hand_verts; tverts = p.obj_verts; tfaces = p.obj_faces;
        slots = p.hitsB;
        P = p.Nh; T = p.Fo; Nv = p.No; chunk = p.chunkB;
        tlim = min(p.Fo, p.ofsplit[b]); plim = p.Nh;
    }

    int tStart = c * chunk;
    if (tStart >= tlim) return;               // block-uniform (slots unread)
    if (pb * PTS_PER_BLK >= plim) return;     // block-uniform (slots unread)
    int nTri = min(tStart + chunk, tlim) - tStart;

    if (tid < nTri) {
        int t = tStart + tid;
        tri_pre_one(tverts + (size_t)b * Nv * 3,
                    tfaces + ((size_t)b * T + t) * 3,
                    s_tri + (size_t)tid * 4);
    }

    int p1 = pb * PTS_PER_BLK + tid;
    int p2 = p1 + 256;
    bool act1 = p1 < plim, act2 = p2 < plim;
    float q1x = 0.f, q1y = 0.f, q1z = 0.f;
    float q2x = 0.f, q2y = 0.f, q2z = 0.f;
    if (act1) {
        const float* q = pts + ((size_t)b * P + p1) * 3;
        q1x = q[0]; q1y = q[1]; q1z = q[2];
    }
    if (act2) {
        const float* q = pts + ((size_t)b * P + p2) * 3;
        q2x = q[0]; q2y = q[1]; q2z = q[2];
    }
    __syncthreads();

    if (!act1) return;                        // act1 false => act2 false
    int cnt1 = 0, cnt2 = 0;
    for (int i = 0; i < nTri; ++i) {
        const float4 f0 = s_tri[(i<<2)+0];
        const float4 f1 = s_tri[(i<<2)+1];
        const float4 f2 = s_tri[(i<<2)+2];
        const float4 f3 = s_tri[(i<<2)+3];
        cnt1 += mt_test(q1x, q1y, q1z, f0, f1, f2, f3);
        cnt2 += mt_test(q2x, q2y, q2z, f0, f1, f2, f3);
    }
    int* base = slots + ((size_t)(c * p.B + b)) * P;
    base[p1] = cnt1;                          // plain stores, no atomics
    if (act2) base[p2] = cnt2;
}

// ---------------------------------------------------------------------------
// One argmin wave. Packed (dist<<32)|idx min => np.argmin tie-break.
// ---------------------------------------------------------------------------
__device__ __forceinline__ void min_one(const Params& p, int w, int lane) {
#pragma clang fp contract(off)
    int nHand = p.B * p.Nh;
    const float* refv; const float* loopv; int loopN; float* outp;
    if (w < nHand) {
        int b = w / p.Nh;
        int n = w - b * p.Nh;
        refv  = p.hand_verts + ((size_t)b * p.Nh + n) * 3;
        loopv = p.obj_verts + (size_t)b * p.No * 3;
        loopN = p.ovsplit[b];
        outp  = p.anchor_h + (size_t)b * p.Nh + n;
    } else {
        int j = w - nHand;
        int b = j / p.No;
        int m = j - b * p.No;
        if (m >= p.ovsplit[b]) return;
        refv  = p.obj_verts + ((size_t)b * p.No + m) * 3;
        loopv = p.hand_verts + (size_t)b * p.Nh * 3;
        loopN = p.Nh;
        outp  = p.anchor_o + (size_t)b * p.No + m;
    }
    float hx = refv[0], hy = refv[1], hz = refv[2];
    float rx = (hx*hx + hy*hy) + hz*hz;
    unsigned long long best = ~0ull;
    for (int m = lane; m < loopN; m += 64) {
        float ox = loopv[m*3+0], oy = loopv[m*3+1], oz = loopv[m*3+2];
        float ry = (ox*ox + oy*oy) + oz*oz;
        float zz = (hx*ox + hy*oy) + hz*oz;
        float d = (rx + ry) - 2.0f * zz;
        unsigned long long e = ((unsigned long long)__float_as_uint(d) << 32) | (unsigned)m;
        if (e < best) best = e;
    }
    for (int off = 32; off > 0; off >>= 1) {
        unsigned long long o = __shfl_xor(best, off, 64);
        if (o < best) best = o;
    }
    if (lane == 0) {
        int idx = (best == ~0ull) ? 0 : (int)(best & 0xffffffffu);
        const float* cv = loopv + (size_t)idx * 3;
        float dx = cv[0] - hx, dy = cv[1] - hy, dz = cv[2] - hz;
        *outp = sqrtf((dx*dx + dy*dy) + dz*dz);
    }
}

// ---------------------------------------------------------------------------
// mega: [raycast VBs | argmin blocks] — no tail sync; resets done counter.
// ---------------------------------------------------------------------------
__global__ __launch_bounds__(256) void mega(Params p) {
    __shared__ float4 s_tri[MAXCHUNK_F4];
    const int tid = threadIdx.x;
    const int bid = blockIdx.x;
    if (bid == 0 && tid == 0) *p.done = 0u;   // visible to reduce_fin at boundary
    const int nRay = p.blocksA + p.blocksB;
    if (bid < nRay) {
        raycast_vb(p, bid, tid, s_tri);
    } else {
        int w = (bid - nRay) * 4 + (tid >> 6);
        if (w < p.B * (p.Nh + p.No)) min_one(p, w, tid & 63);
    }
}

// ---------------------------------------------------------------------------
// reduce_fin: block b = batch b. Sums per-chunk slots (parity) + tanh means;
// last-done block (8-way counter + fences — cheap at 8 blocks) finalizes.
// ---------------------------------------------------------------------------
__global__ __launch_bounds__(1024) void reduce_fin(Params p) {
    const int b = blockIdx.x, tid = threadIdx.x;
    const int wave = tid >> 6, lane = tid & 63;
    float s0=0.f,s1=0.f,s2=0.f,s3=0.f,s4=0.f,s5=0.f;

    int tlimB = min(p.Fo, p.ofsplit[b]);
    int nCB = (tlimB + p.chunkB - 1) / p.chunkB;        // valid pass-B chunks
    for (int n = tid; n < p.Nh; n += 1024) {
        int par = 0;
        for (int c = 0; c < nCB; ++c)
            par += p.hitsB[((size_t)(c * p.B + b)) * p.Nh + n];
        bool ext = (par & 1) == 0;
        float val = 25.0f * tanhf(p.anchor_h[(size_t)b*p.Nh + n] / 25.0f);
        if (ext) { s0 += val; s1 += 1.0f; } else { s2 += val; s3 += 1.0f; }
    }
    int split = p.ovsplit[b];
    for (int m = tid; m < split; m += 1024) {
        int par = 0;
        for (int c = 0; c < p.CA; ++c)
            par += p.hitsA[((size_t)(c * p.B + b)) * p.No + m];
        if (par & 1) {                                   // interior & valid
            s4 += 25.0f * tanhf(p.anchor_o[(size_t)b*p.No + m] / 25.0f);
            s5 += 1.0f;
        }
    }
    for (int off = 32; off > 0; off >>= 1) {
        s0 += __shfl_xor(s0, off, 64);
        s1 += __shfl_xor(s1, off, 64);
        s2 += __shfl_xor(s2, off, 64);
        s3 += __shfl_xor(s3, off, 64);
        s4 += __shfl_xor(s4, off, 64);
        s5 += __shfl_xor(s5, off, 64);
    }
    __shared__ float red[16][6];
    __shared__ bool s_last;
    if (lane == 0) {
        red[wave][0]=s0; red[wave][1]=s1; red[wave][2]=s2;
        red[wave][3]=s3; red[wave][4]=s4; red[wave][5]=s5;
    }
    __syncthreads();
    if (tid == 0) {
        float t0=0.f,t1=0.f,t2=0.f,t3=0.f,t4=0.f,t5=0.f;
        for (int wv = 0; wv < 16; ++wv) {
            t0 += red[wv][0]; t1 += red[wv][1]; t2 += red[wv][2];
            t3 += red[wv][3]; t4 += red[wv][4]; t5 += red[wv][5];
        }
        p.out[2 + b]  = (t1 > 0.f) ? t0 / fmaxf(t1, 1.f) : 0.f;
        float ph      = (t3 > 0.f) ? t2 / fmaxf(t3, 1.f) : 0.f;
        float po      = (t5 > 0.f) ? t4 / fmaxf(t5, 1.f) : 0.f;
        p.out[10 + b] = ph + po;
        float* pp = p.partials + b * 6;
        pp[0]=t0; pp[1]=t1; pp[2]=t2; pp[3]=t3; pp[4]=t4; pp[5]=t5;
        __threadfence();                     // release partials
        unsigned int old = atomicAdd(p.done, 1u);
        s_last = (old == (unsigned int)(gridDim.x - 1));
    }
    __syncthreads();
    if (!s_last || tid != 0) return;
    __threadfence();                         // acquire others' partials
    float sm=0.f,cm=0.f,sph=0.f,cph=0.f,spo=0.f,cpo=0.f;
    for (int bb = 0; bb < p.B; ++bb) {
        const float* pp = p.partials + bb * 6;
        sm  += pp[0]; cm  += pp[1]; sph += pp[2];
        cph += pp[3]; spo += pp[4]; cpo += pp[5];
    }
    float missed = (cm  > 0.f) ? sm  / fmaxf(cm , 1.f) : 0.f;
    float ph     = (cph > 0.f) ? sph / fmaxf(cph, 1.f) : 0.f;
    float po     = (cpo > 0.f) ? spo / fmaxf(cpo, 1.f) : 0.f;
    p.out[0] = missed;
    p.out[1] = ph + po;
}

// ---------------------------------------------------------------------------
extern "C" void kernel_launch(void* const* d_in, const int* in_sizes, int n_in,
                              void* d_out, int out_size, void* d_ws, size_t ws_size,
                              hipStream_t stream) {
    Params p;
    p.hand_verts = (const float*)d_in[0];
    p.hand_faces = (const int*)d_in[1];
    p.obj_verts  = (const float*)d_in[2];
    p.obj_faces  = (const int*)d_in[3];
    p.ovsplit    = (const int*)d_in[4];
    p.ofsplit    = (const int*)d_in[5];
    p.out        = (float*)d_out;

    p.B  = in_sizes[4];
    p.Nh = in_sizes[0] / (3 * p.B);
    p.Fh = in_sizes[1] / (3 * p.B);
    p.No = in_sizes[2] / (3 * p.B);
    p.Fo = in_sizes[3] / (3 * p.B);

    p.CA = 16; p.CB = 32;
    p.chunkA = (p.Fh + p.CA - 1) / p.CA;       // 97  for Fh=1538 (388 f4 <= 512)
    p.chunkB = (p.Fo + p.CB - 1) / p.CB;       // 125 for Fo=4000 (500 f4 <= 512)
    p.pbA = (p.No + PTS_PER_BLK - 1) / PTS_PER_BLK;   // 4
    p.pbB = (p.Nh + PTS_PER_BLK - 1) / PTS_PER_BLK;   // 2
    p.blocksA = p.pbA * p.CA * p.B;            // 512
    p.blocksB = p.pbB * p.CB * p.B;            // 512

    char* ws = (char*)d_ws;
    size_t off = 0;
    auto alloc = [&](size_t bytes) -> void* {
        void* q = ws + off;
        off = (off + bytes + 255) & ~(size_t)255;
        return q;
    };
    p.hitsA    = (int*)   alloc((size_t)p.CA * p.B * p.No * sizeof(int));
    p.hitsB    = (int*)   alloc((size_t)p.CB * p.B * p.Nh * sizeof(int));
    p.anchor_h = (float*) alloc((size_t)p.B * p.Nh * sizeof(float));
    p.anchor_o = (float*) alloc((size_t)p.B * p.No * sizeof(float));
    p.partials = (float*) alloc((size_t)p.B * 6 * sizeof(float));
    p.done     = (unsigned int*)alloc(sizeof(unsigned int));

    int totalMin   = p.B * (p.Nh + p.No);
    int nMinBlocks = (totalMin + 3) / 4;       // 4 argmin waves per block
    int grid = p.blocksA + p.blocksB + nMinBlocks;

    mega<<<grid, 256, 0, stream>>>(p);
    reduce_fin<<<p.B, 1024, 0, stream>>>(p);
}